// Round 8
// baseline (501.101 us; speedup 1.0000x reference)
//
#include <hip/hip_runtime.h>
#include <math.h>

#define NN 100000      // nodes
#define CD 32          // classes / hidden
#define NPB 4          // nodes (waves) per block in fused layer kernel
#define LGRID 2048     // persistent layer blocks

#define SCAN_EPB 512                                   // counts per scan block
#define SCAN_NB  ((NN + SCAN_EPB - 1) / SCAN_EPB)      // 196 blocks

__device__ __forceinline__ float4 max4(float4 a, float4 b) {
    float4 r;
    r.x = fmaxf(a.x, b.x); r.y = fmaxf(a.y, b.y);
    r.z = fmaxf(a.z, b.z); r.w = fmaxf(a.w, b.w);
    return r;
}
__device__ __forceinline__ float2 max2(float2 a, float2 b) {
    float2 r; r.x = fmaxf(a.x, b.x); r.y = fmaxf(a.y, b.y); return r;
}

// ---------------------------------------------------------------------------
__global__ void detect_idx64(const void* edge, int* flag) {
    const long long* p = (const long long*)edge;
    int lane = threadIdx.x & 63;
    int bad = 0;
    for (int i = lane; i < 512; i += 64) {
        long long v = p[i];
        if (v < 0 || v >= NN) bad = 1;
    }
    unsigned long long anybad = __ballot(bad);
    if (lane == 0) *flag = (anybad == 0ULL) ? 1 : 0;
}

__device__ __forceinline__ int load_idx(const void* edge, int i, int is64) {
    if (is64) return (int)((const long long*)edge)[i];
    return ((const int*)edge)[i];
}

// ---------------------------------------------------------------------------
// CSR build (packed counters; cursor aliases counts).
__global__ void hist_kernel(const void* edge, int E, const int* flag,
                            int* __restrict__ counts) {
    const int is64 = *flag;
    int e = blockIdx.x * blockDim.x + threadIdx.x;
    if (e >= E) return;
    int dst = load_idx(edge, E + e, is64);
    atomicAdd(&counts[dst], 1);            // fire & forget
}

__global__ void scan_partial_kernel(const int* __restrict__ counts,
                                    int* __restrict__ blockSums) {
    __shared__ int red[256];
    const int b = blockIdx.x, t = threadIdx.x;
    const int base = b * SCAN_EPB + t * 2;
    int s = 0;
    if (base < NN)     s += counts[base];
    if (base + 1 < NN) s += counts[base + 1];
    red[t] = s;
    __syncthreads();
    for (int off = 128; off > 0; off >>= 1) {
        if (t < off) red[t] += red[t + off];
        __syncthreads();
    }
    if (t == 0) blockSums[b] = red[0];
}

__global__ void scan_bases_kernel(int* blockSums) {
    __shared__ int tmp[SCAN_NB];
    const int t = threadIdx.x;
    if (t < SCAN_NB) tmp[t] = blockSums[t];
    __syncthreads();
    if (t == 0) {
        int run = 0;
        for (int i = 0; i < SCAN_NB; ++i) { int c = tmp[i]; tmp[i] = run; run += c; }
    }
    __syncthreads();
    if (t < SCAN_NB) blockSums[t] = tmp[t];
}

__global__ void scan_final_kernel(const int* __restrict__ counts,
                                  const int* __restrict__ blockSums,
                                  int* __restrict__ offsets,
                                  int* __restrict__ cursor) {
    __shared__ int tsum[256];
    const int b = blockIdx.x, t = threadIdx.x;
    const int base = b * SCAN_EPB + t * 2;
    const int c0 = (base < NN)     ? counts[base]     : 0;
    const int c1 = (base + 1 < NN) ? counts[base + 1] : 0;
    tsum[t] = c0 + c1;
    __syncthreads();
    for (int off = 1; off < 256; off <<= 1) {
        int u = (t >= off) ? tsum[t - off] : 0;
        __syncthreads();
        tsum[t] += u;
        __syncthreads();
    }
    const int bbase = blockSums[b];
    const int excl  = tsum[t] - (c0 + c1);
    if (base < NN) {
        int o = bbase + excl;
        offsets[base] = o; cursor[base] = o;
        if (base + 1 < NN) {
            int o1 = o + c0;
            offsets[base + 1] = o1; cursor[base + 1] = o1;
        }
    }
    if (b == SCAN_NB - 1 && t == 255) offsets[NN] = bbase + tsum[255];  // == E
}

// 4 edges/thread straight-line: 4 independent atomicAdds in flight.
__global__ void fill_kernel(const void* edge, int E, const int* flag,
                            int* cursor, int* __restrict__ csr_src) {
    const int is64 = *flag;
    const int st   = blockDim.x;
    const int e0   = blockIdx.x * (st * 4) + threadIdx.x;
    const int e1 = e0 + st, e2 = e0 + 2 * st, e3 = e0 + 3 * st;
    const bool v0 = e0 < E, v1 = e1 < E, v2 = e2 < E, v3 = e3 < E;

    int s0 = 0, d0 = 0, s1 = 0, d1 = 0, s2 = 0, d2 = 0, s3 = 0, d3 = 0;
    if (v0) { s0 = load_idx(edge, e0, is64); d0 = load_idx(edge, E + e0, is64); }
    if (v1) { s1 = load_idx(edge, e1, is64); d1 = load_idx(edge, E + e1, is64); }
    if (v2) { s2 = load_idx(edge, e2, is64); d2 = load_idx(edge, E + e2, is64); }
    if (v3) { s3 = load_idx(edge, e3, is64); d3 = load_idx(edge, E + e3, is64); }

    int p0 = 0, p1 = 0, p2 = 0, p3 = 0;
    if (v0) p0 = atomicAdd(&cursor[d0], 1);
    if (v1) p1 = atomicAdd(&cursor[d1], 1);
    if (v2) p2 = atomicAdd(&cursor[d2], 1);
    if (v3) p3 = atomicAdd(&cursor[d3], 1);

    if (v0) csr_src[p0] = s0;
    if (v1) csr_src[p1] = s1;
    if (v2) csr_src[p2] = s2;
    if (v3) csr_src[p3] = s3;
}

// ---------------------------------------------------------------------------
// Fused SAGE layer, persistent blocks, barrier-free inner loop.
// Weights live in REGISTERS (per-lane column, k split across wave halves).
// Gather: vectorized (float4 for DIN=32, float2 for DIN=50), multi-edge per
// wave with shfl_xor cross-edge reduction. sAgg/sH in LDS, read via uniform
// ds_read_b128 in the dense phase. MODE: 0 = relu, 2 = log_softmax.
template <int DIN, int MODE>
__global__ void sage_layer_kernel(const float* __restrict__ h,
                                  const int* __restrict__ offsets,
                                  const int* __restrict__ csr_src,
                                  const float* __restrict__ Wl,
                                  const float* __restrict__ bl,
                                  const float* __restrict__ Wr,
                                  float* __restrict__ out) {
    constexpr int KH = (DIN == 32) ? 16 : 28;   // k-range per wave half
    constexpr int ST = (DIN == 32) ? 32 : 56;   // LDS row stride (floats, 16B-div)

    __shared__ __align__(16) float sAgg[NPB][ST];
    __shared__ __align__(16) float sH[NPB][ST];

    const int tid  = threadIdx.x;
    const int g    = tid >> 6;          // wave id = local node slot
    const int lane = tid & 63;
    const int p    = lane >> 5;         // wave half
    const int j    = lane & 31;         // output column
    const int k0   = p * KH;

    // Per-lane weight columns in registers (zero-padded past DIN).
    float rWl[KH], rWr[KH];
#pragma unroll
    for (int kk = 0; kk < KH; ++kk) {
        const int k = k0 + kk;
        const bool v = (k < DIN);
        rWl[kk] = v ? Wl[k * CD + j] : 0.0f;
        rWr[kk] = v ? Wr[k * CD + j] : 0.0f;
    }
    const float rB = bl[j];

    // Zero LDS pad (k in [DIN, 2*KH)) once — rWl/rWr are 0 there, but
    // 0 * garbage(NaN) would poison; pads are never overwritten below.
    if (DIN == 50 && p == 1 && j < 3) {
        sAgg[g][50 + 2 * j] = 0.0f; sAgg[g][51 + 2 * j] = 0.0f;
        sH[g][50 + 2 * j]   = 0.0f; sH[g][51 + 2 * j]   = 0.0f;
    }

    const float NEG = -INFINITY;
    const int ngrp = (NN + NPB - 1) / NPB;

    for (int grp = blockIdx.x; grp < ngrp; grp += gridDim.x) {
        const int n = grp * NPB + g;
        if (n < NN) {
            const int beg = offsets[n];
            const int end = offsets[n + 1];
            if (DIN == 32) {
                // lane = e*8 + c : 8 edges × 8 float4 chunks; unroll x2.
                const int e = lane >> 3;
                const int c = lane & 7;
                float4 A0 = {NEG, NEG, NEG, NEG};
                float4 A1 = {NEG, NEG, NEG, NEG};
                int i = beg;
                for (; i + 16 <= end; i += 16) {
                    int s0 = csr_src[i + e];
                    int s1 = csr_src[i + 8 + e];
                    float4 v0 = *(const float4*)&h[(size_t)s0 * 32 + c * 4];
                    float4 v1 = *(const float4*)&h[(size_t)s1 * 32 + c * 4];
                    A0 = max4(A0, v0);
                    A1 = max4(A1, v1);
                }
                if (i + e < end) {
                    int s0 = csr_src[i + e];
                    A0 = max4(A0, *(const float4*)&h[(size_t)s0 * 32 + c * 4]);
                }
                if (i + 8 + e < end) {
                    int s1 = csr_src[i + 8 + e];
                    A1 = max4(A1, *(const float4*)&h[(size_t)s1 * 32 + c * 4]);
                }
                A0 = max4(A0, A1);
                #pragma unroll
                for (int off = 8; off <= 32; off <<= 1) {
                    float4 t;
                    t.x = __shfl_xor(A0.x, off); t.y = __shfl_xor(A0.y, off);
                    t.z = __shfl_xor(A0.z, off); t.w = __shfl_xor(A0.w, off);
                    A0 = max4(A0, t);
                }
                A0.x = (A0.x == NEG) ? 0.0f : A0.x;
                A0.y = (A0.y == NEG) ? 0.0f : A0.y;
                A0.z = (A0.z == NEG) ? 0.0f : A0.z;
                A0.w = (A0.w == NEG) ? 0.0f : A0.w;
                if (lane < 8) {
                    *(float4*)&sAgg[g][lane * 4] = A0;
                } else if (lane < 16) {
                    const int c2 = lane - 8;
                    float4 own = *(const float4*)&h[(size_t)n * 32 + c2 * 4];
                    *(float4*)&sH[g][c2 * 4] = own;
                }
            } else {
                // halves = 2 edges, float2 chunks c<25, unroll x4 (8 in flight).
                const int c = j;
                const bool ac = (c < 25);
                float2 A0 = {NEG, NEG}, A1 = {NEG, NEG};
                float2 A2 = {NEG, NEG}, A3 = {NEG, NEG};
                int i = beg + p;
                for (; i + 6 < end; i += 8) {
                    int s0 = csr_src[i];
                    int s1 = csr_src[i + 2];
                    int s2 = csr_src[i + 4];
                    int s3 = csr_src[i + 6];
                    if (ac) {
                        A0 = max2(A0, *(const float2*)&h[(size_t)s0 * 50 + 2 * c]);
                        A1 = max2(A1, *(const float2*)&h[(size_t)s1 * 50 + 2 * c]);
                        A2 = max2(A2, *(const float2*)&h[(size_t)s2 * 50 + 2 * c]);
                        A3 = max2(A3, *(const float2*)&h[(size_t)s3 * 50 + 2 * c]);
                    }
                }
                if (ac) {
                    if (i < end)
                        A0 = max2(A0, *(const float2*)&h[(size_t)csr_src[i] * 50 + 2 * c]);
                    if (i + 2 < end)
                        A1 = max2(A1, *(const float2*)&h[(size_t)csr_src[i + 2] * 50 + 2 * c]);
                    if (i + 4 < end)
                        A2 = max2(A2, *(const float2*)&h[(size_t)csr_src[i + 4] * 50 + 2 * c]);
                }
                A0 = max2(A0, A1); A2 = max2(A2, A3); A0 = max2(A0, A2);
                A0.x = fmaxf(A0.x, __shfl_xor(A0.x, 32));
                A0.y = fmaxf(A0.y, __shfl_xor(A0.y, 32));
                A0.x = (A0.x == NEG) ? 0.0f : A0.x;
                A0.y = (A0.y == NEG) ? 0.0f : A0.y;
                if (p == 0 && ac) {
                    *(float2*)&sAgg[g][2 * c] = A0;
                } else if (p == 1 && ac) {
                    float2 own = *(const float2*)&h[(size_t)n * 50 + 2 * c];
                    *(float2*)&sH[g][2 * c] = own;
                }
            }
        }
        // no barrier: same-wave LDS write -> read (compiler orders via lgkmcnt)

        if (n < NN) {
            float part = (p == 0) ? rB : 0.0f;
#pragma unroll
            for (int it = 0; it < KH / 4; ++it) {
                float4 a  = *(const float4*)&sAgg[g][k0 + it * 4];
                float4 hh = *(const float4*)&sH[g][k0 + it * 4];
                part += a.x  * rWl[it * 4]     + a.y  * rWl[it * 4 + 1]
                      + a.z  * rWl[it * 4 + 2] + a.w  * rWl[it * 4 + 3];
                part += hh.x * rWr[it * 4]     + hh.y * rWr[it * 4 + 1]
                      + hh.z * rWr[it * 4 + 2] + hh.w * rWr[it * 4 + 3];
            }
            float acc = part + __shfl_xor(part, 32);
            if (lane < 32) {
                if (MODE == 0) acc = fmaxf(acc, 0.0f);
                if (MODE == 2) {
                    float m = acc;
                    for (int off = 16; off > 0; off >>= 1) m = fmaxf(m, __shfl_xor(m, off, 32));
                    float ex = expf(acc - m);
                    float s = ex;
                    for (int off = 16; off > 0; off >>= 1) s += __shfl_xor(s, off, 32);
                    acc = acc - m - logf(s);
                }
                out[(size_t)n * CD + j] = acc;
            }
        }
    }
}

// ---------------------------------------------------------------------------
extern "C" void kernel_launch(void* const* d_in, const int* in_sizes, int n_in,
                              void* d_out, int out_size, void* d_ws, size_t ws_size,
                              hipStream_t stream) {
    const float* x    = (const float*)d_in[0];
    const void*  edge = d_in[1];
    const float* Wl1 = (const float*)d_in[2];
    const float* bl1 = (const float*)d_in[3];
    const float* Wr1 = (const float*)d_in[4];
    const float* Wl2 = (const float*)d_in[5];
    const float* bl2 = (const float*)d_in[6];
    const float* Wr2 = (const float*)d_in[7];
    const float* Wl3 = (const float*)d_in[8];
    const float* bl3 = (const float*)d_in[9];
    const float* Wr3 = (const float*)d_in[10];

    const int E = in_sizes[1] / 2;

    // Workspace carve-up (256B aligned). Total ≈ 32.8 MB (ws budget ~32 MiB).
    char* ws = (char*)d_ws;
    size_t off = 0;
    auto carve = [&](size_t bytes) {
        void* p = ws + off;
        off = (off + bytes + 255) & ~(size_t)255;
        return p;
    };
    int*   counts    = (int*)  carve((size_t)NN * 4);       // aliased as cursor
    int*   cursor    = counts;
    int*   offsets   = (int*)  carve((size_t)(NN + 1) * 4);
    int*   flag      = (int*)  carve(4);
    int*   blockSums = (int*)  carve((size_t)SCAN_NB * 4);
    int*   csr_src   = (int*)  carve((size_t)E * 4);
    float* h1        = (float*)carve((size_t)NN * CD * 4);
    float* h2        = (float*)carve((size_t)NN * CD * 4);
    float* out       = (float*)d_out;
    (void)ws_size; (void)n_in; (void)out_size;

    hipMemsetAsync(counts, 0, (size_t)NN * 4, stream);
    detect_idx64<<<1, 64, 0, stream>>>(edge, flag);

    const int eb1 = (E + 255) / 256;
    const int eb4 = (E + 1023) / 1024;
    hist_kernel<<<eb1, 256, 0, stream>>>(edge, E, flag, counts);
    scan_partial_kernel<<<SCAN_NB, 256, 0, stream>>>(counts, blockSums);
    scan_bases_kernel<<<1, 256, 0, stream>>>(blockSums);
    scan_final_kernel<<<SCAN_NB, 256, 0, stream>>>(counts, blockSums, offsets, cursor);
    fill_kernel<<<eb4, 256, 0, stream>>>(edge, E, flag, cursor, csr_src);

    sage_layer_kernel<50, 0><<<LGRID, 256, 0, stream>>>(x,  offsets, csr_src, Wl1, bl1, Wr1, h1);
    sage_layer_kernel<32, 0><<<LGRID, 256, 0, stream>>>(h1, offsets, csr_src, Wl2, bl2, Wr2, h2);
    sage_layer_kernel<32, 2><<<LGRID, 256, 0, stream>>>(h2, offsets, csr_src, Wl3, bl3, Wr3, out);
}